// Round 3
// baseline (535.786 us; speedup 1.0000x reference)
//
#include <hip/hip_runtime.h>
#include <math.h>

// Signed ECE == (sum(conf) - sum(acc)) / N  -- binning cancels algebraically.
// logits [N=1e6, C=100] fp32 row-major. 16 threads per row -> each wave load
// instruction covers 4 rows x 256 B CONTIGUOUS segments (vs 16 x 64 B before).

#define N_ROWS 1000000
#define N_COLS 100
#define BLOCK 256
#define ROWS_PER_TILE (BLOCK / 16)       // 16 rows per block-iteration
#define N_TILES (N_ROWS / ROWS_PER_TILE) // 62500, exact
#define GRID 2500                        // 25 tiles per block, exact

typedef float vfloat4 __attribute__((ext_vector_type(4)));  // clang-native for nontemporal

__global__ __launch_bounds__(BLOCK) void ece_main(
    const float* __restrict__ logits,
    const int* __restrict__ labels,
    float* __restrict__ partials)
{
    const int t = threadIdx.x;
    const int r = t >> 4;        // row-in-tile 0..15
    const int l = t & 15;        // lane-in-row 0..15

    float local = 0.0f;

    for (int tile = blockIdx.x; tile < N_TILES; tile += GRID) {
        const int row = tile * ROWS_PER_TILE + r;
        const vfloat4* rowp = reinterpret_cast<const vfloat4*>(
            logits + (size_t)row * N_COLS);

        // Load 1: float4 index l (cols 4l..4l+3) -- 16 lanes x 16 B = 256 B
        // contiguous per row per wave instruction.
        const vfloat4 a = __builtin_nontemporal_load(rowp + l);
        float vmax = a.x; int imax = 4 * l;
        if (a.y > vmax) { vmax = a.y; imax = 4 * l + 1; }
        if (a.z > vmax) { vmax = a.z; imax = 4 * l + 2; }
        if (a.w > vmax) { vmax = a.w; imax = 4 * l + 3; }

        // Load 2 (row tail, cols 64..99): float4 index 16+l for l<9.
        if (l < 9) {
            const vfloat4 b = __builtin_nontemporal_load(rowp + 16 + l);
            const int c = 64 + 4 * l;
            if (b.x > vmax) { vmax = b.x; imax = c;     }
            if (b.y > vmax) { vmax = b.y; imax = c + 1; }
            if (b.z > vmax) { vmax = b.z; imax = c + 2; }
            if (b.w > vmax) { vmax = b.w; imax = c + 3; }
        }

        // Width-16 butterfly max/argmax; tie -> smaller col (jnp.argmax).
#pragma unroll
        for (int m = 1; m <= 8; m <<= 1) {
            const float vo = __shfl_xor(vmax, m, 16);
            const int   io = __shfl_xor(imax, m, 16);
            if (vo > vmax || (vo == vmax && io < imax)) { vmax = vo; imax = io; }
        }

        if (l == 0) {
            const float conf = 1.0f / (1.0f + expf(-vmax));
            const float acc  = (imax == labels[row]) ? 1.0f : 0.0f;
            local += conf - acc;
        }
    }

    // Block reduction: 64-wide wave sum (non-leaders hold 0), then LDS.
#pragma unroll
    for (int off = 32; off > 0; off >>= 1) local += __shfl_down(local, off, 64);

    __shared__ float wsum[BLOCK / 64];
    if ((t & 63) == 0) wsum[t >> 6] = local;
    __syncthreads();
    if (t == 0) {
        float b = 0.0f;
#pragma unroll
        for (int w = 0; w < BLOCK / 64; ++w) b += wsum[w];
        partials[blockIdx.x] = b;
    }
}

__global__ __launch_bounds__(BLOCK) void ece_finalize(
    const float* __restrict__ partials, float* __restrict__ out)
{
    double s = 0.0;
    for (int i = threadIdx.x; i < GRID; i += BLOCK) s += (double)partials[i];
#pragma unroll
    for (int off = 32; off > 0; off >>= 1) s += __shfl_down(s, off, 64);

    __shared__ double wsum[BLOCK / 64];
    if ((threadIdx.x & 63) == 0) wsum[threadIdx.x >> 6] = s;
    __syncthreads();
    if (threadIdx.x == 0) {
        double b = 0.0;
#pragma unroll
        for (int w = 0; w < BLOCK / 64; ++w) b += wsum[w];
        out[0] = (float)(b / (double)N_ROWS);
    }
}

extern "C" void kernel_launch(void* const* d_in, const int* in_sizes, int n_in,
                              void* d_out, int out_size, void* d_ws, size_t ws_size,
                              hipStream_t stream)
{
    const float* logits = (const float*)d_in[0];
    const int*   labels = (const int*)d_in[1];
    float*       out    = (float*)d_out;
    float*       partials = (float*)d_ws;   // 2500 * 4 B = 10 KB

    ece_main<<<GRID, BLOCK, 0, stream>>>(logits, labels, partials);
    ece_finalize<<<1, BLOCK, 0, stream>>>(partials, out);
}

// Round 4
// 532.247 us; speedup vs baseline: 1.0066x; 1.0066x over previous
//
#include <hip/hip_runtime.h>
#include <math.h>

// Signed ECE == (sum(conf) - sum(acc)) / N  -- binning cancels algebraically.
// Strategy: stream logits [1e6 x 100] fp32 through LDS with copy-like flat
// float4 loads (64 lanes x 16 B contiguous per wave instr), then reduce
// max/argmax per row out of LDS. 125 rows/tile, 8000 blocks.

#define N_ROWS 1000000
#define N_COLS 100
#define BLOCK 256
#define TILE_ROWS 125
#define F4_PER_TILE (TILE_ROWS * 25)   // 3125 float4 per tile (50 KB)
#define N_TILES (N_ROWS / TILE_ROWS)   // 8000, exact
#define LDS_STRIDE 108                 // dwords per row (pad 100 -> 108; 432 B, 16B-aligned)

typedef float vfloat4 __attribute__((ext_vector_type(4)));

__global__ __launch_bounds__(BLOCK) void ece_main(
    const float* __restrict__ logits,
    const int* __restrict__ labels,
    float* __restrict__ partials)
{
    __shared__ float lds[TILE_ROWS * LDS_STRIDE];   // 54,000 B
    __shared__ float wsum[BLOCK / 64];

    const int t = threadIdx.x;
    const int tile = blockIdx.x;

    // ---- Stage: flat contiguous float4 reads of the 50 KB tile ----
    const vfloat4* gsrc = reinterpret_cast<const vfloat4*>(
        logits + (size_t)tile * TILE_ROWS * N_COLS);

    int j = t;
    for (; j + BLOCK < F4_PER_TILE; j += 2 * BLOCK) {
        const vfloat4 a = gsrc[j];
        const vfloat4 b = gsrc[j + BLOCK];
        const int r0 = j / 25,        c0 = j - 25 * r0;
        const int r1 = (j + BLOCK) / 25, c1 = (j + BLOCK) - 25 * r1;
        *reinterpret_cast<vfloat4*>(&lds[r0 * LDS_STRIDE + c0 * 4]) = a;
        *reinterpret_cast<vfloat4*>(&lds[r1 * LDS_STRIDE + c1 * 4]) = b;
    }
    if (j < F4_PER_TILE) {
        const vfloat4 a = gsrc[j];
        const int r0 = j / 25, c0 = j - 25 * r0;
        *reinterpret_cast<vfloat4*>(&lds[r0 * LDS_STRIDE + c0 * 4]) = a;
    }
    __syncthreads();

    // ---- Reduce: 2 threads per row; halves overlap (0..51 and 48..99) so
    //      both do a uniform 13 x ds_read_b128 scan. Overlap is benign for
    //      first-occurrence argmax (see combine rule below). ----
    float local = 0.0f;
    if (t < 2 * TILE_ROWS) {
        const int r = t >> 1;
        const int h = t & 1;
        const int start = h ? 48 : 0;           // starting column
        const float* rowp = &lds[r * LDS_STRIDE + start];

        float vmax = -INFINITY;
        int   imax = 0;
#pragma unroll
        for (int k = 0; k < 13; ++k) {
            const vfloat4 v = *reinterpret_cast<const vfloat4*>(rowp + 4 * k);
            const int c = start + 4 * k;
            if (v.x > vmax) { vmax = v.x; imax = c;     }
            if (v.y > vmax) { vmax = v.y; imax = c + 1; }
            if (v.z > vmax) { vmax = v.z; imax = c + 2; }
            if (v.w > vmax) { vmax = v.w; imax = c + 3; }
        }

        // Combine the pair: take partner's only if strictly greater.
        // (h=0 covers 0..51, h=1 covers 48..99; on ties the h=0 result has
        //  the smaller first-occurrence index -- matches jnp.argmax.)
        const float vp = __shfl_xor(vmax, 1, 2);
        const int   ip = __shfl_xor(imax, 1, 2);
        if (vp > vmax) { vmax = vp; imax = ip; }

        if (h == 0) {
            const float conf = 1.0f / (1.0f + expf(-vmax));
            const float acc  = (imax == labels[tile * TILE_ROWS + r]) ? 1.0f : 0.0f;
            local = conf - acc;
        }
    }

    // ---- Block sum -> one partial per block ----
#pragma unroll
    for (int off = 32; off > 0; off >>= 1) local += __shfl_down(local, off, 64);
    if ((t & 63) == 0) wsum[t >> 6] = local;
    __syncthreads();
    if (t == 0) {
        float b = 0.0f;
#pragma unroll
        for (int w = 0; w < BLOCK / 64; ++w) b += wsum[w];
        partials[blockIdx.x] = b;
    }
}

__global__ __launch_bounds__(BLOCK) void ece_finalize(
    const float* __restrict__ partials, float* __restrict__ out)
{
    double s = 0.0;
    for (int i = threadIdx.x; i < N_TILES; i += BLOCK) s += (double)partials[i];
#pragma unroll
    for (int off = 32; off > 0; off >>= 1) s += __shfl_down(s, off, 64);

    __shared__ double dsum[BLOCK / 64];
    if ((threadIdx.x & 63) == 0) dsum[threadIdx.x >> 6] = s;
    __syncthreads();
    if (threadIdx.x == 0) {
        double b = 0.0;
#pragma unroll
        for (int w = 0; w < BLOCK / 64; ++w) b += dsum[w];
        out[0] = (float)(b / (double)N_ROWS);
    }
}

extern "C" void kernel_launch(void* const* d_in, const int* in_sizes, int n_in,
                              void* d_out, int out_size, void* d_ws, size_t ws_size,
                              hipStream_t stream)
{
    const float* logits = (const float*)d_in[0];
    const int*   labels = (const int*)d_in[1];
    float*       out    = (float*)d_out;
    float*       partials = (float*)d_ws;   // 8000 * 4 B = 32 KB

    ece_main<<<N_TILES, BLOCK, 0, stream>>>(logits, labels, partials);
    ece_finalize<<<1, BLOCK, 0, stream>>>(partials, out);
}